// Round 10
// baseline (218.060 us; speedup 1.0000x reference)
//
#include <hip/hip_runtime.h>
#include <math.h>

#define DIM 128
// ws float layout:
//   G^(2^s) f32, s=0..5 : GP(s) = s*16384       (GP(0) = E^64 from k_ps2)
//   Y[j] f32, j=0..63   : YOFFI + j*8192
//   Xa^q (q=1..8)       : XOFF(q-1)   (Xa = 16*dt*A, entries O(1))
//   T_i (i=1..64)       : TOFF(i)
//   Wf f16 frags        : float idx FWOFFI (64 mats x 16384 halves)
//   Yf f16 frags        : float idx FYOFFI (64 mats x 8192 halves)
#define GP(s)    ((s) * 16384)
#define YOFFI    (65 * 16384)
#define XOFF(q)  ((97 + (q)) * 16384)
#define TOFF(i)  ((105 + (i) - 1) * 16384)
#define FWOFFI   (169 * 16384)
#define FYOFFI   (201 * 16384)
#define ALPHA    16.0f

typedef _Float16 f16x8 __attribute__((ext_vector_type(8)));
typedef float    f32x4 __attribute__((ext_vector_type(4)));

__device__ __forceinline__ float4 ld4(const float* p) { return *(const float4*)p; }

__device__ __forceinline__ void stageA(const float* __restrict__ A, float* AT, int tid)
{
    for (int idx = tid; idx < DIM * DIM; idx += 256)
        AT[(idx & 127) * 132 + (idx >> 7)] = A[idx];
}

__device__ __forceinline__ void mm_core(const float* AT, const float* Bs,
                                        float (&acc)[4][4], int tid)
{
    int d0 = (tid & 31) * 4, c0 = (tid >> 5) * 4;
    #pragma unroll 4
    for (int k = 0; k < DIM; k++) {
        float4 a4 = ld4(&AT[k * 132 + d0]);
        float4 b4 = ld4(&Bs[k * 36 + c0]);
        float a_[4] = {a4.x, a4.y, a4.z, a4.w};
        float b_[4] = {b4.x, b4.y, b4.z, b4.w};
        #pragma unroll
        for (int i = 0; i < 4; i++)
            #pragma unroll
            for (int j = 0; j < 4; j++) acc[i][j] += a_[i] * b_[j];
    }
}

// ---- L1: Xa (redundant per WG) + Xa^2 panel; Y0 f32+frags; W0 frags -------
__global__ __launch_bounds__(256) void k_x2(const float* __restrict__ t,
                                            const float* __restrict__ x0,
                                            const float* __restrict__ S,
                                            const float* __restrict__ D,
                                            float* __restrict__ ws)
{
    __shared__ __align__(16) float AT[DIM * 132];
    __shared__ __align__(16) float Bs[DIM * 36];
    int tid = threadIdx.x, bid = blockIdx.x, cpan = bid * 32;
    float sc = (t[1] - t[0]) * ALPHA;
    for (int e = tid; e < 16384; e += 256) {
        int r = e >> 7, c = e & 127;
        float a;
        if (r == c)      a = -log1pf(expf(D[r]));
        else if (r < c)  a =  S[(r * (2 * DIM - r - 1)) / 2 + (c - r - 1)];
        else             a = -S[(c * (2 * DIM - c - 1)) / 2 + (r - c - 1)];
        a *= sc;
        AT[c * 132 + r] = a;
        if (c >= cpan && c < cpan + 32) Bs[r * 36 + (c - cpan)] = a;
        if (bid == 0) ws[XOFF(0) + e] = a;
    }
    if (bid == 1) for (int e = tid; e < 8192; e += 256) ws[YOFFI + e] = x0[e];
    if (bid == 2) {                                  // W0 = I fragment table
        _Float16* Wf = (_Float16*)(ws + FWOFFI);
        for (int ch = tid; ch < 2048; ch += 256) {
            int m = ch >> 4, k0 = (ch & 15) << 3;
            f16x8 hv;
            #pragma unroll
            for (int q = 0; q < 8; q++) hv[q] = (m == k0 + q) ? (_Float16)1.0f : (_Float16)0.0f;
            int lane = (m & 15) | (((k0 >> 3) & 3) << 4);
            size_t off = (((size_t)(m >> 4) * 4 + (k0 >> 5)) * 64 + lane) * 8;
            *(f16x8*)(Wf + off) = hv;
        }
    }
    if (bid == 3) {                                  // Y0 fragment table
        _Float16* Yf = (_Float16*)(ws + FYOFFI);
        for (int slot = tid; slot < 1024; slot += 256) {
            int ls = slot & 63, tile = slot >> 6;
            int n = (tile >> 2) * 16 + (ls & 15);
            int k0 = (tile & 3) * 32 + ((ls >> 4) & 3) * 8;
            f16x8 hv;
            #pragma unroll
            for (int q = 0; q < 8; q++) hv[q] = (_Float16)x0[(size_t)(k0 + q) * 64 + n];
            *(f16x8*)(Yf + (size_t)slot * 8) = hv;
        }
    }
    __syncthreads();
    float acc[4][4] = {};
    mm_core(AT, Bs, acc, tid);
    int d0 = (tid & 31) * 4, c0 = (tid >> 5) * 4;
    #pragma unroll
    for (int r = 0; r < 4; r++) {
        float4 st = make_float4(acc[r][0], acc[r][1], acc[r][2], acc[r][3]);
        *(float4*)&ws[XOFF(1) + (size_t)(d0 + r) * DIM + cpan + c0] = st;
    }
}

// ---- MFMA hi/lo atom: C(f32) = A(f32) @ B(f32), optional Y-frag emission --
struct Jobs { int4 jb[33]; };

__global__ __launch_bounds__(256) void k_mm(float* __restrict__ ws, Jobs jobs)
{
    __shared__ __align__(16) _Float16 fB[2][16384];     // 64 KB; reused as C
    const int4 jb = jobs.jb[blockIdx.x];
    const int ncols = jb.w & 255;
    const int fragj = (jb.w >> 8) - 1;
    const float* A = ws + jb.x;
    const float* B = ws + jb.y;
    float* C = ws + jb.z;
    const int tid = threadIdx.x, wave = tid >> 6, lane = tid & 63;

    // A -> registers, MFMA A-frag order (wave owns rows [32w, 32w+32))
    f16x8 ah[2][4], al[2][4];
    #pragma unroll
    for (int mt = 0; mt < 2; mt++)
        #pragma unroll
        for (int kc = 0; kc < 4; kc++) {
            int m = wave * 32 + mt * 16 + (lane & 15);
            int k0 = kc * 32 + ((lane >> 4) & 3) * 8;
            const float* src = A + (size_t)m * DIM + k0;
            float4 p = ld4(src), r = ld4(src + 4);
            float v[8] = {p.x, p.y, p.z, p.w, r.x, r.y, r.z, r.w};
            f16x8 h8, l8;
            #pragma unroll
            for (int q = 0; q < 8; q++) {
                _Float16 h = (_Float16)v[q];
                h8[q] = h; l8[q] = (_Float16)(v[q] - (float)h);
            }
            ah[mt][kc] = h8; al[mt][kc] = l8;
        }

    // B -> LDS, MFMA B-frag order (hi/lo)
    const int nslots = (DIM * ncols) >> 3;
    for (int slot = tid; slot < nslots; slot += 256) {
        int ls = slot & 63, tile = slot >> 6;
        int n = (tile >> 2) * 16 + (ls & 15);
        int k0 = (tile & 3) * 32 + ((ls >> 4) & 3) * 8;
        f16x8 h8, l8;
        #pragma unroll
        for (int q = 0; q < 8; q++) {
            float v = B[(size_t)(k0 + q) * ncols + n];
            _Float16 h = (_Float16)v;
            h8[q] = h; l8[q] = (_Float16)(v - (float)h);
        }
        *(f16x8*)&fB[0][(size_t)slot * 8] = h8;
        *(f16x8*)&fB[1][(size_t)slot * 8] = l8;
    }
    __syncthreads();

    const int NT = ncols >> 4;
    f32x4 acc[2][8] = {};
    for (int kc = 0; kc < 4; kc++) {
        #pragma unroll
        for (int nt = 0; nt < 8; nt++) {
            if (nt >= NT) break;
            size_t bo = ((size_t)(nt * 4 + kc) * 64 + lane) * 8;
            f16x8 bh = *(const f16x8*)&fB[0][bo];
            f16x8 bl = *(const f16x8*)&fB[1][bo];
            #pragma unroll
            for (int mt = 0; mt < 2; mt++) {
                acc[mt][nt] = __builtin_amdgcn_mfma_f32_16x16x32_f16(ah[mt][kc], bh, acc[mt][nt], 0, 0, 0);
                acc[mt][nt] = __builtin_amdgcn_mfma_f32_16x16x32_f16(ah[mt][kc], bl, acc[mt][nt], 0, 0, 0);
                acc[mt][nt] = __builtin_amdgcn_mfma_f32_16x16x32_f16(al[mt][kc], bh, acc[mt][nt], 0, 0, 0);
            }
        }
    }
    __syncthreads();

    // C staging in LDS (reuse fB), then coalesced f32 store + optional frags
    float* Cst = (float*)&fB[0][0];
    #pragma unroll
    for (int mt = 0; mt < 2; mt++)
        #pragma unroll
        for (int nt = 0; nt < 8; nt++) {
            if (nt >= NT) break;
            int row = wave * 32 + mt * 16 + ((lane >> 4) << 2);
            int n = nt * 16 + (lane & 15);
            #pragma unroll
            for (int p = 0; p < 4; p++)
                Cst[(size_t)(row + p) * ncols + n] = acc[mt][nt][p];
        }
    __syncthreads();
    for (int e = tid * 4; e < DIM * ncols; e += 1024)
        *(float4*)&C[e] = ld4(&Cst[e]);
    if (fragj >= 0) {
        _Float16* Yf = (_Float16*)(ws + FYOFFI) + (size_t)fragj * 8192;
        for (int slot = tid; slot < 1024; slot += 256) {
            int ls = slot & 63, tile = slot >> 6;
            int n = (tile >> 2) * 16 + (ls & 15);
            int k0 = (tile & 3) * 32 + ((ls >> 4) & 3) * 8;
            f16x8 hv;
            #pragma unroll
            for (int q = 0; q < 8; q++) hv[q] = (_Float16)Cst[(size_t)(k0 + q) * 64 + n];
            *(f16x8*)(Yf + (size_t)slot * 8) = hv;
        }
    }
}

// ---- L4: T_i = Xa8 @ P2(i) + P1(i), i=1..64; c'_n = (i/16)^n/n! -----------
__global__ __launch_bounds__(256) void k_ps1(float* __restrict__ ws)
{
    __shared__ __align__(16) float AT[DIM * 132];
    __shared__ __align__(16) float Bs[DIM * 36];
    int i = blockIdx.x + 1, cpan = blockIdx.y * 32, tid = threadIdx.x;
    float r = (float)i / ALPHA;
    float c[24]; c[0] = 1.0f;
    #pragma unroll
    for (int n = 1; n < 24; n++) c[n] = c[n - 1] * (r / (float)n);
    stageA(ws + XOFF(7), AT, tid);
    for (int idx = tid; idx < DIM * 8; idx += 256) {
        int k = idx >> 3, cc4 = (idx & 7) * 4;
        float4 b = make_float4(0.f, 0.f, 0.f, 0.f);
        #pragma unroll
        for (int q = 1; q < 8; q++) {
            float4 x = ld4(&ws[XOFF(q - 1) + (size_t)k * DIM + cpan + cc4]);
            b.x += c[16 + q] * x.x; b.y += c[16 + q] * x.y;
            b.z += c[16 + q] * x.z; b.w += c[16 + q] * x.w;
        }
        int col = cpan + cc4;
        if (k >= col && k < col + 4) (&b.x)[k - col] += c[16];
        *(float4*)&Bs[k * 36 + cc4] = b;
    }
    __syncthreads();
    float acc[4][4] = {};
    mm_core(AT, Bs, acc, tid);
    int d0 = (tid & 31) * 4, c0 = (tid >> 5) * 4;
    float* T = ws + TOFF(i);
    #pragma unroll
    for (int rr = 0; rr < 4; rr++) {
        int dd = d0 + rr;
        float add[4] = {0.f, 0.f, 0.f, 0.f};
        #pragma unroll
        for (int q = 1; q < 8; q++) {
            float4 x = ld4(&ws[XOFF(q - 1) + (size_t)dd * DIM + cpan + c0]);
            add[0] += c[8 + q] * x.x; add[1] += c[8 + q] * x.y;
            add[2] += c[8 + q] * x.z; add[3] += c[8 + q] * x.w;
        }
        int col0 = cpan + c0;
        if (dd >= col0 && dd < col0 + 4) add[dd - col0] += c[8];
        float4 st = make_float4(acc[rr][0] + add[0], acc[rr][1] + add[1],
                                acc[rr][2] + add[2], acc[rr][3] + add[3]);
        *(float4*)&T[(size_t)dd * DIM + cpan + c0] = st;
    }
}

// ---- L5: E^i = Xa8 @ T_i + P0(i); i<64 -> Wf frags, i=64 -> G f32 ---------
__global__ __launch_bounds__(256) void k_ps2(float* __restrict__ ws)
{
    __shared__ __align__(16) float AT[DIM * 132];
    __shared__ __align__(16) float Bs[DIM * 36];
    int i = blockIdx.x + 1, cpan = blockIdx.y * 32, tid = threadIdx.x;
    float r = (float)i / ALPHA;
    float c[8]; c[0] = 1.0f;
    #pragma unroll
    for (int n = 1; n < 8; n++) c[n] = c[n - 1] * (r / (float)n);
    stageA(ws + XOFF(7), AT, tid);
    const float* T = ws + TOFF(i);
    for (int idx = tid; idx < DIM * 32; idx += 256) {
        int k = idx >> 5, cc = idx & 31;
        Bs[k * 36 + cc] = T[(size_t)k * DIM + cpan + cc];
    }
    __syncthreads();
    float acc[4][4] = {};
    mm_core(AT, Bs, acc, tid);
    int d0 = (tid & 31) * 4, c0 = (tid >> 5) * 4;
    #pragma unroll
    for (int rr = 0; rr < 4; rr++) {
        int dd = d0 + rr;
        float add[4] = {0.f, 0.f, 0.f, 0.f};
        #pragma unroll
        for (int q = 1; q < 8; q++) {
            float4 x = ld4(&ws[XOFF(q - 1) + (size_t)dd * DIM + cpan + c0]);
            add[0] += c[q] * x.x; add[1] += c[q] * x.y;
            add[2] += c[q] * x.z; add[3] += c[q] * x.w;
        }
        int col0 = cpan + c0;
        if (dd >= col0 && dd < col0 + 4) add[dd - col0] += 1.0f;
        #pragma unroll
        for (int j = 0; j < 4; j++) acc[rr][j] += add[j];
    }
    if (i == 64) {
        float* G = ws + GP(0);
        #pragma unroll
        for (int rr = 0; rr < 4; rr++) {
            float4 st = make_float4(acc[rr][0], acc[rr][1], acc[rr][2], acc[rr][3]);
            *(float4*)&G[(size_t)(d0 + rr) * DIM + cpan + c0] = st;
        }
        return;
    }
    __syncthreads();
    #pragma unroll
    for (int rr = 0; rr < 4; rr++)
        #pragma unroll
        for (int j = 0; j < 4; j++) Bs[(d0 + rr) * 36 + c0 + j] = acc[rr][j];
    __syncthreads();
    _Float16* Wf = (_Float16*)(ws + FWOFFI);
    for (int ch = tid; ch < 512; ch += 256) {
        int m = ch >> 2, k0l = (ch & 3) * 8, k0 = cpan + k0l;
        f16x8 hv;
        #pragma unroll
        for (int q = 0; q < 8; q++) hv[q] = (_Float16)Bs[m * 36 + k0l + q];
        int lane = (m & 15) | (((k0 >> 3) & 3) << 4);
        size_t off = (size_t)i * 16384 + (((size_t)(m >> 4) * 4 + (k0 >> 5)) * 64 + lane) * 8;
        *(f16x8*)(Wf + off) = hv;
    }
}

// ---- L12: out[64j+i] = W_i @ Y_j via MFMA (batch-major stores) ------------
__global__ __launch_bounds__(256) void k_final(const _Float16* __restrict__ Wf,
                                               const _Float16* __restrict__ Yf,
                                               float* __restrict__ out)
{
    int i = blockIdx.x, j = blockIdx.y;
    int tid = threadIdx.x, wave = tid >> 6, lane = tid & 63;
    const _Float16* Ab = Yf + (size_t)j * 8192;
    const _Float16* Bb = Wf + (size_t)i * 16384;
    f32x4 acc[4][2] = {};
    #pragma unroll
    for (int ks = 0; ks < 4; ks++) {
        f16x8 a[4], b[2];
        #pragma unroll
        for (int bt = 0; bt < 4; bt++)
            a[bt] = *(const f16x8*)(Ab + (((size_t)bt * 4 + ks) * 64 + lane) * 8);
        #pragma unroll
        for (int nn = 0; nn < 2; nn++)
            b[nn] = *(const f16x8*)(Bb + (((size_t)(wave * 2 + nn) * 4 + ks) * 64 + lane) * 8);
        #pragma unroll
        for (int bt = 0; bt < 4; bt++)
            #pragma unroll
            for (int nn = 0; nn < 2; nn++)
                acc[bt][nn] = __builtin_amdgcn_mfma_f32_16x16x32_f16(a[bt], b[nn], acc[bt][nn], 0, 0, 0);
    }
    float* slab = out + (size_t)(j * 64 + i) * 8192;
    int nlo = lane & 15, b0 = (lane >> 4) * 4;
    #pragma unroll
    for (int bt = 0; bt < 4; bt++)
        #pragma unroll
        for (int nn = 0; nn < 2; nn++) {
            int n = (wave * 2 + nn) * 16 + nlo;
            __builtin_nontemporal_store(acc[bt][nn],
                (f32x4*)&slab[(size_t)n * 64 + bt * 16 + b0]);
        }
}

static inline void addjob(Jobs& J, int& n, int a, int b, int c, int ncols, int fragj)
{
    J.jb[n++] = make_int4(a, b, c, ncols | ((fragj + 1) << 8));
}

extern "C" void kernel_launch(void* const* d_in, const int* in_sizes, int n_in,
                              void* d_out, int out_size, void* d_ws, size_t ws_size,
                              hipStream_t stream)
{
    const float* t  = (const float*)d_in[0];
    const float* x0 = (const float*)d_in[1];
    const float* S  = (const float*)d_in[2];
    const float* D  = (const float*)d_in[3];
    float* out = (float*)d_out;
    float* ws  = (float*)d_ws;
    _Float16* Wf = (_Float16*)(ws + FWOFFI);
    _Float16* Yf = (_Float16*)(ws + FYOFFI);

    // L1: Xa, Xa^2 (+Y0 f32+frags, W0 frags)
    hipLaunchKernelGGL(k_x2, dim3(4), dim3(256), 0, stream, t, x0, S, D, ws);

    Jobs J; int n;
    // L2: Xa3 = Xa2*Xa ; Xa4 = Xa2*Xa2
    n = 0;
    addjob(J, n, XOFF(1), XOFF(0), XOFF(2), 128, -1);
    addjob(J, n, XOFF(1), XOFF(1), XOFF(3), 128, -1);
    hipLaunchKernelGGL(k_mm, dim3(n), dim3(256), 0, stream, ws, J);
    // L3: Xa5..Xa8 = Xa4 * Xa1..Xa4
    n = 0;
    for (int q = 1; q <= 4; q++) addjob(J, n, XOFF(3), XOFF(q - 1), XOFF(3 + q), 128, -1);
    hipLaunchKernelGGL(k_mm, dim3(n), dim3(256), 0, stream, ws, J);

    // L4/L5: Paterson-Stockmeyer for E^1..E^64 (f32, full chip)
    hipLaunchKernelGGL(k_ps1, dim3(64, 4), dim3(256), 0, stream, ws);
    hipLaunchKernelGGL(k_ps2, dim3(64, 4), dim3(256), 0, stream, ws);

    // L6..L11: G-squarings + Y doubling (MFMA atoms, Y-frags emitted inline)
    n = 0;  // d=0: G2 ; Y1
    addjob(J, n, GP(0), GP(0), GP(1), 128, -1);
    addjob(J, n, GP(0), YOFFI, YOFFI + 8192, 64, 1);
    hipLaunchKernelGGL(k_mm, dim3(n), dim3(256), 0, stream, ws, J);
    n = 0;  // d=1: G4 ; Y2,Y3
    addjob(J, n, GP(1), GP(1), GP(2), 128, -1);
    addjob(J, n, GP(1), YOFFI,        YOFFI + 2 * 8192, 64, 2);
    addjob(J, n, GP(1), YOFFI + 8192, YOFFI + 3 * 8192, 64, 3);
    hipLaunchKernelGGL(k_mm, dim3(n), dim3(256), 0, stream, ws, J);
    n = 0;  // d=2: G8 ; Y4..7
    addjob(J, n, GP(2), GP(2), GP(3), 128, -1);
    for (int jj = 0; jj < 4; jj++)
        addjob(J, n, GP(2), YOFFI + jj * 8192, YOFFI + (4 + jj) * 8192, 64, 4 + jj);
    hipLaunchKernelGGL(k_mm, dim3(n), dim3(256), 0, stream, ws, J);
    n = 0;  // d=3: G16 ; Y8..15
    addjob(J, n, GP(3), GP(3), GP(4), 128, -1);
    for (int jj = 0; jj < 8; jj++)
        addjob(J, n, GP(3), YOFFI + jj * 8192, YOFFI + (8 + jj) * 8192, 64, 8 + jj);
    hipLaunchKernelGGL(k_mm, dim3(n), dim3(256), 0, stream, ws, J);
    n = 0;  // d=4: G32 ; Y16..31
    addjob(J, n, GP(4), GP(4), GP(5), 128, -1);
    for (int jj = 0; jj < 16; jj++)
        addjob(J, n, GP(4), YOFFI + jj * 8192, YOFFI + (16 + jj) * 8192, 64, 16 + jj);
    hipLaunchKernelGGL(k_mm, dim3(n), dim3(256), 0, stream, ws, J);
    n = 0;  // d=5: Y32..63
    for (int jj = 0; jj < 32; jj++)
        addjob(J, n, GP(5), YOFFI + jj * 8192, YOFFI + (32 + jj) * 8192, 64, 32 + jj);
    hipLaunchKernelGGL(k_mm, dim3(n), dim3(256), 0, stream, ws, J);

    // L12: out[64j+i] = W_i @ Y_j
    hipLaunchKernelGGL(k_final, dim3(64, 64), dim3(256), 0, stream, Wf, Yf, out);
}